// Round 13
// baseline (21.868 us; speedup 1.0000x reference)
//
#include <hip/hip_runtime.h>
#include <math.h>

#define NB 6   // GRID_N + K basis functions

struct Params {
    float k3, k6;     // ki0/3, ki0/6  (y0,y1 from Lt1,Lt2)
    float kA, kC;     // ki0/(2 ln2), ki0/(6 ln2)
    float sb1;
};

__device__ __forceinline__ float fexp2(float x) { return __builtin_amdgcn_exp2f(x); }
__device__ __forceinline__ float flog2(float x) { return __builtin_amdgcn_logf(x); }
__device__ __forceinline__ float frcp(float x)  { return __builtin_amdgcn_rcpf(x); }
__device__ __forceinline__ float frsq(float x)  { return __builtin_amdgcn_rsqf(x); }

#define CW 1.44269504f          // 1/ln2
#define PSI_W 0.28125f          // y half-window for psi0/psi1
#define PSI_IS 3.5555556f       // 1/PSI_W

// register-cubic eval: v = A0+f(A1+f(A2+f A3)), d = B0+f(B1+f(B2+f B3))
__device__ __forceinline__ void cub2(float f, float4 A, float4 B,
                                     float& v, float& d) {
    v = fmaf(fmaf(fmaf(A.w, f, A.z), f, A.y), f, A.x);
    d = fmaf(fmaf(fmaf(B.w, f, B.z), f, B.y), f, B.x);
}

// psi0/psi1: two windows [-W,0] (cell 6) / [0,W] (cell 7), select on y<0.
__device__ __forceinline__ void psi_eval(float y, float4 Al, float4 Bl,
                                         float4 Ah, float4 Bh,
                                         float& v, float& d) {
    bool lo = y < 0.0f;
    float f = fmaf(y, PSI_IS, lo ? 1.0f : 0.0f);
    float4 A = lo ? Al : Ah;
    float4 B = lo ? Bl : Bh;
    cub2(f, A, B, v, d);
}

__device__ __forceinline__ float silu_d(float x) {
    float sig = frcp(1.0f + fexp2(-1.44269504f * x));
    return sig * fmaf(x, 1.0f - sig, 1.0f);
}

// layer-2 spline derivative from LDS (deriv-only table, r12-clampless)
__device__ __forceinline__ float spline_d(float x, const float4* __restrict__ tD) {
    float u = fmaf(x, 1.5f, 5.5f);
    int   i = (int)u;
    float f = u - (float)i;
    float4 B = tD[i];
    return fmaf(fmaf(B.z, f, B.y), f, B.x);
}

// exact spline value+deriv for the BUILDER (generic, clamped)
__device__ float spline_exact(float x, const float* cp, float& dv) {
    float u = fmaf(x, 1.5f, 5.5f);
    int i = (int)u;
    i = i < 0 ? 0 : (i > 11 ? 11 : i);
    bool real = (i >= 1 && i <= 9);
    int c = i - 1;
    float cv[4];
#pragma unroll
    for (int kk = 0; kk < 4; ++kk) {
        int j = c + kk - 3;
        cv[kk] = (real && j >= 0 && j < NB) ? cp[j] : 0.0f;
    }
    const float c16 = 1.0f / 6.0f;
    float a0 = (cv[0] + 4.0f * cv[1] + cv[2]) * c16;
    float a1 = (cv[2] - cv[0]) * 0.5f;
    float a2 = (cv[0] - 2.0f * cv[1] + cv[2]) * 0.5f;
    float a3 = (cv[3] - cv[0] + 3.0f * (cv[1] - cv[2])) * c16;
    float f = u - (float)i;
    dv = 1.5f * (a1 + f * fmaf(3.0f * a3, f, 2.0f * a2));
    return a0 + f * (a1 + f * fmaf(a3, f, a2));
}

// 4-node (f = 0,1/3,2/3,1) interpolating cubic coeffs (r10-validated pattern)
__device__ __forceinline__ float4 interp4(float V0, float V1, float V2, float V3) {
    return make_float4(V0,
                       -5.5f * V0 + 9.0f * V1 - 4.5f * V2 + V3,
                        9.0f * V0 - 22.5f * V1 + 18.0f * V2 - 4.5f * V3,
                       -4.5f * V0 + 13.5f * V1 - 13.5f * V2 + 4.5f * V3);
}

__global__ __launch_bounds__(256) void kan_grad(
        const float* __restrict__ strain, float* __restrict__ out, int n,
        const float* __restrict__ c0, const float* __restrict__ sb0,
        const float* __restrict__ sp0, const float* __restrict__ b0,
        const float* __restrict__ c1, const float* __restrict__ sb1,
        const float* __restrict__ sp1, const float* __restrict__ ki0,
        const float* __restrict__ ki1) {
    __shared__ float4 psi[10];    // {A,B} x {e0lo,e0hi,e1lo,e1hi,e2}
    __shared__ float4 tabD[12];   // layer-2 deriv-only cells

    const int t = threadIdx.x;

    Params P;
    float k = ki0[0], l = ki1[0];
    P.k3 = k * (1.0f / 3.0f);
    P.k6 = k * (1.0f / 6.0f);
    P.kA = k * 0.72134752f;       // k/(2 ln2)
    P.kC = k * 0.24044917f;       // k/(6 ln2)
    P.sb1 = sb1[0];

    if (t < 5) {
        // build psi windows: t=0 e0lo, 1 e0hi, 2 e1lo, 3 e1hi, 4 e2(L-space)
        int  e    = (t < 2) ? 0 : (t < 4) ? 1 : 2;
        bool isLo = (t == 0 || t == 2);
        float w0 = (e == 2) ? -0.1f : (isLo ? -PSI_W : 0.0f);
        float ws = (e == 2) ? 0.8f : PSI_W;
        float sb = sb0[e], sp = sp0[e];
        const float* cp = c0 + e * NB;
        float bias = (e == 0) ? b0[0] : 0.0f;
        float cLv = l * 0.34657359f;           // x2 = cLv * L
        float V[4], D[4];
#pragma unroll
        for (int mm = 0; mm < 4; ++mm) {
            float yv = w0 + ws * ((float)mm * (1.0f / 3.0f));
            float x, chain;
            if (e < 2) { x = exp2f(yv); chain = x * 0.69314718f; }
            else       { x = cLv * yv; chain = cLv; }
            float sd;
            float sv = spline_exact(x, cp, sd);
            float sig = 1.0f / (1.0f + expf(-x));
            float si  = x * sig;
            float dsi = sig * fmaf(x, 1.0f - sig, 1.0f);
            V[mm] = bias + sb * si + sp * sv;
            D[mm] = (sb * dsi + sp * sd) * chain;
        }
        psi[2 * t]     = interp4(V[0], V[1], V[2], V[3]);
        psi[2 * t + 1] = interp4(D[0], D[1], D[2], D[3]);
    }
    if (t >= 8 && t < 20) {
        // layer-2 deriv table (sp1-scaled), 12 cells, pads zero
        int cell = t - 8;
        bool real = (cell >= 1 && cell <= 9);
        float scale = sp1[0];
        int c = cell - 1;
        float cv[4];
#pragma unroll
        for (int kk = 0; kk < 4; ++kk) {
            int j = c + kk - 3;
            cv[kk] = (real && j >= 0 && j < NB) ? c1[j] : 0.0f;
        }
        float a1 = (cv[2] - cv[0]) * 0.5f * scale;
        float a2 = (cv[0] - 2.0f * cv[1] + cv[2]) * 0.5f * scale;
        float a3 = (cv[3] - cv[0] + 3.0f * (cv[1] - cv[2])) * (1.0f / 6.0f) * scale;
        tabD[cell] = make_float4(1.5f * a1, 3.0f * a2, 4.5f * a3, 0.0f);
    }
    __syncthreads();

    // preload psi coefficients into registers (loop-invariant)
    const float4 A0l = psi[0], B0l = psi[1], A0h = psi[2], B0h = psi[3];
    const float4 A1l = psi[4], B1l = psi[5], A1h = psi[6], B1h = psi[7];
    const float4 A2  = psi[8], B2  = psi[9];

    // ---- per-thread analytic g0 at s=0: Lt=0 -> y0=y1=0 (hi, f=0), L=0
    // (f2=0.125); irr=0 -> t-term/g2 vanish; invt=invDet=1 -> G=kA(R0+R1)+2C.
    {
        // done below after helpers; compute inline:
    }
    float S2g, D2g;
    cub2(0.125f, A2, B2, S2g, D2g);
    float hacc0 = A0h.x + A1h.x + S2g;
    float dW0 = fmaf(P.sb1, silu_d(hacc0), spline_d(hacc0, tabD));
    float R0g = dW0 * B0h.x, R1g = dW0 * B1h.x, R2g = dW0 * D2g;
    float Cg  = fmaf(-P.kC, R0g + R1g, CW * R2g);
    const float G = P.kA * (R0g + R1g) + 2.0f * Cg;   // g0 = (G, G, 0)

    const int ngroups = (n + 3) >> 2;  // 4 samples (= 3 float4) per thread-task
    for (int gi = blockIdx.x * blockDim.x + t; gi < ngroups;
         gi += gridDim.x * blockDim.x) {
        int i0 = gi * 4;
        if (i0 + 4 <= n) {
            const float4* sp4 = reinterpret_cast<const float4*>(strain + (size_t)i0 * 3);
            float4 v0 = sp4[0], v1 = sp4[1], v2 = sp4[2];
            float in[12] = { v0.x, v0.y, v0.z, v0.w,
                             v1.x, v1.y, v1.z, v1.w,
                             v2.x, v2.y, v2.z, v2.w };
            float o[12];
#pragma unroll
            for (int kk = 0; kk < 4; ++kk) {
                float s1 = in[3 * kk], s2 = in[3 * kk + 1], b = in[3 * kk + 2];
                float q   = s1 - s2;
                float m   = s1 + s2 + 1.0f;
                float h2  = fmaf(q, q, b * b);
                float irr = h2 > 0.0f ? frsq(h2) : 0.0f;   // JAX where
                float r   = h2 * irr;
                float t1  = m - r, t2 = m + r;
                float invDet = frcp(t1 * t2);
                float invt1 = t2 * invDet, invt2 = t1 * invDet;
                float Lt1 = flog2(t1), Lt2 = flog2(t2);
                float y0 = fmaf(Lt1, P.k3, -Lt2 * P.k6);
                float y1 = fmaf(Lt2, P.k3, -Lt1 * P.k6);
                float Ls = Lt1 + Lt2;

                float p0v, p0d, p1v, p1d, p2v, p2d;
                psi_eval(y0, A0l, B0l, A0h, B0h, p0v, p0d);
                psi_eval(y1, A1l, B1l, A1h, B1h, p1v, p1d);
                cub2(fmaf(Ls, 1.25f, 0.125f), A2, B2, p2v, p2d);

                float hacc = p0v + p1v + p2v;
                float dWdh = fmaf(P.sb1, silu_d(hacc), spline_d(hacc, tabD));

                float R0 = dWdh * p0d;
                float R1 = dWdh * p1d;
                float R2 = dWdh * p2d;
                float A = P.kA * R0 * invt1;
                float B = P.kA * R1 * invt2;
                float C = invDet * fmaf(-P.kC, R0 + R1, CW * R2);
                float u0 = (B - A) * irr;
                float w  = fmaf(C, m, 0.5f * (A + B));
                float tt = q * fmaf(0.5f, u0, -C);
                o[3 * kk]     = 2.0f * (w + tt) - G;
                o[3 * kk + 1] = 2.0f * (w - tt) - G;
                o[3 * kk + 2] = b * fmaf(-2.0f, C, u0);
            }
            float4* op4 = reinterpret_cast<float4*>(out + (size_t)i0 * 3);
            op4[0] = make_float4(o[0], o[1], o[2],  o[3]);
            op4[1] = make_float4(o[4], o[5], o[6],  o[7]);
            op4[2] = make_float4(o[8], o[9], o[10], o[11]);
        } else {
            for (int i = i0; i < n; ++i) {
                float s1 = strain[3 * i], s2 = strain[3 * i + 1], b = strain[3 * i + 2];
                float q   = s1 - s2;
                float m   = s1 + s2 + 1.0f;
                float h2  = fmaf(q, q, b * b);
                float irr = h2 > 0.0f ? frsq(h2) : 0.0f;
                float r   = h2 * irr;
                float t1  = m - r, t2 = m + r;
                float invDet = frcp(t1 * t2);
                float invt1 = t2 * invDet, invt2 = t1 * invDet;
                float Lt1 = flog2(t1), Lt2 = flog2(t2);
                float y0 = fmaf(Lt1, P.k3, -Lt2 * P.k6);
                float y1 = fmaf(Lt2, P.k3, -Lt1 * P.k6);
                float Ls = Lt1 + Lt2;
                float p0v, p0d, p1v, p1d, p2v, p2d;
                psi_eval(y0, A0l, B0l, A0h, B0h, p0v, p0d);
                psi_eval(y1, A1l, B1l, A1h, B1h, p1v, p1d);
                cub2(fmaf(Ls, 1.25f, 0.125f), A2, B2, p2v, p2d);
                float hacc = p0v + p1v + p2v;
                float dWdh = fmaf(P.sb1, silu_d(hacc), spline_d(hacc, tabD));
                float R0 = dWdh * p0d;
                float R1 = dWdh * p1d;
                float R2 = dWdh * p2d;
                float A = P.kA * R0 * invt1;
                float B = P.kA * R1 * invt2;
                float C = invDet * fmaf(-P.kC, R0 + R1, CW * R2);
                float u0 = (B - A) * irr;
                float w  = fmaf(C, m, 0.5f * (A + B));
                float tt = q * fmaf(0.5f, u0, -C);
                out[3 * i]     = 2.0f * (w + tt) - G;
                out[3 * i + 1] = 2.0f * (w - tt) - G;
                out[3 * i + 2] = b * fmaf(-2.0f, C, u0);
            }
        }
    }
}

extern "C" void kernel_launch(void* const* d_in, const int* in_sizes, int n_in,
                              void* d_out, int out_size, void* d_ws, size_t ws_size,
                              hipStream_t stream) {
    const float* strain = (const float*)d_in[0];
    const float* c0  = (const float*)d_in[1];
    const float* sb0 = (const float*)d_in[2];
    const float* sp0 = (const float*)d_in[3];
    const float* b0  = (const float*)d_in[4];
    const float* c1  = (const float*)d_in[5];
    const float* sb1 = (const float*)d_in[6];
    const float* sp1 = (const float*)d_in[7];
    // d_in[8] = b1: no effect on gradient
    const float* ki0 = (const float*)d_in[9];
    const float* ki1 = (const float*)d_in[10];

    int n = in_sizes[0] / 3;                 // number of samples
    int ngroups = (n + 3) / 4;
    int block = 256;
    int grid = (ngroups + block - 1) / block;
    if (grid > 8192) grid = 8192;

    kan_grad<<<grid, block, 0, stream>>>(strain, (float*)d_out, n,
                                         c0, sb0, sp0, b0, c1, sb1, sp1, ki0, ki1);
}

// Round 14
// 19.257 us; speedup vs baseline: 1.1356x; 1.1356x over previous
//
#include <hip/hip_runtime.h>
#include <math.h>

#define NB 6   // GRID_N + K basis functions

struct Params {
    float sb0_0, sb0_1, sb0_2;
    float b0, sb1;
    float k3, k6, kh;   // ki0/3, ki0/6, ki0/2
    float cL;           // ki1 * 0.5 * ln2
    float ch;           // ki1 * 0.5
};

__device__ __forceinline__ float fexp2(float x) { return __builtin_amdgcn_exp2f(x); }
__device__ __forceinline__ float flog2(float x) { return __builtin_amdgcn_logf(x); }
__device__ __forceinline__ float frcp(float x)  { return __builtin_amdgcn_rcpf(x); }
__device__ __forceinline__ float frsq(float x)  { return __builtin_amdgcn_rsqf(x); }

// Zero-padded 12-cell per-spline table (cells 0,10,11 = all-zero pads), rows
// pre-scaled by sp. Cell layout: u = (x+3)/h + 1, real cells 1..9.
// A = {a0,a1,a2,a3} value coeffs; B = {1.5a1, 3a2, 4.5a3, 0} deriv coeffs.
// Out-of-grid x lands in a zero cell -> sp=dsp=0 (matches reference mask).
__device__ __forceinline__ void spline_sd(float x, const float4* __restrict__ t4,
                                          float& sp, float& dsp) {
    float u = fmaf(x, 1.5f, 5.5f);
    int   i = (int)u;                       // trunc == floor for u>=0; u<0 clamps to pad
    i = i < 0 ? 0 : (i > 11 ? 11 : i);
    float f = u - (float)i;
    float4 A = t4[2 * i];
    float4 B = t4[2 * i + 1];
    sp  = fmaf(fmaf(fmaf(A.w, f, A.z), f, A.y), f, A.x);
    dsp = fmaf(fmaf(B.z, f, B.y), f, B.x);
}

__device__ __forceinline__ float spline_d(float x, const float4* __restrict__ t4) {
    float u = fmaf(x, 1.5f, 5.5f);
    int   i = (int)u;
    i = i < 0 ? 0 : (i > 11 ? 11 : i);
    float f = u - (float)i;
    float4 B = t4[2 * i + 1];
    return fmaf(fmaf(B.z, f, B.y), f, B.x);
}

__device__ __forceinline__ void silu_fd(float x, float& s, float& ds) {
    float sig = frcp(1.0f + fexp2(-1.44269504f * x));
    s  = x * sig;
    ds = sig * fmaf(x, 1.0f - sig, 1.0f);
}

__device__ __forceinline__ float silu_d(float x) {
    float sig = frcp(1.0f + fexp2(-1.44269504f * x));
    return sig * fmaf(x, 1.0f - sig, 1.0f);
}

// Analytic gradient, half-coordinate log2-space form (validated r7);
// layer-2 evaluates derivatives only (W value is never needed).
__device__ __forceinline__ void grad_sample(float s1, float s2, float s3,
        const Params& P, const float4* __restrict__ tb, float g[3]) {
    float q   = s1 - s2;
    float m   = s1 + s2 + 1.0f;
    float b   = s3;
    float h2  = fmaf(q, q, b * b);
    float irr = h2 > 0.0f ? frsq(h2) : 0.0f;   // 1/r (0 at h2<=0, JAX where)
    float r   = h2 * irr;
    float t1  = m - r, t2 = m + r;
    float invDet = frcp(t1 * t2);
    float invt1 = t2 * invDet, invt2 = t1 * invDet;
    float Lt1 = flog2(t1), Lt2 = flog2(t2);
    float x0  = fexp2(fmaf(Lt1, P.k3, -Lt2 * P.k6));
    float x1  = fexp2(fmaf(Lt2, P.k3, -Lt1 * P.k6));
    float x2  = (Lt1 + Lt2) * P.cL;

    float S0, D0, S1v, D1, S2v, D2;
    spline_sd(x0, tb,      S0,  D0);
    spline_sd(x1, tb + 24, S1v, D1);
    spline_sd(x2, tb + 48, S2v, D2);
    float si0, dsi0, si1, dsi1, si2, dsi2;
    silu_fd(x0, si0, dsi0);
    silu_fd(x1, si1, dsi1);
    silu_fd(x2, si2, dsi2);
    float hacc = P.b0 + fmaf(P.sb0_0, si0, S0) + fmaf(P.sb0_1, si1, S1v)
               + fmaf(P.sb0_2, si2, S2v);
    float gx0 = fmaf(P.sb0_0, dsi0, D0);
    float gx1 = fmaf(P.sb0_1, dsi1, D1);
    float gx2 = fmaf(P.sb0_2, dsi2, D2);

    float dWdh = fmaf(P.sb1, silu_d(hacc), spline_d(hacc, tb + 72));

    float P0  = dWdh * gx0 * x0;
    float P1  = dWdh * gx1 * x1;
    float w2c = dWdh * gx2;
    float A = P.kh * P0 * invt1;
    float B = P.kh * P1 * invt2;
    float C = invDet * fmaf(-P.k6, P0 + P1, P.ch * w2c);
    float u0 = (B - A) * irr;
    float w  = fmaf(C, m, 0.5f * (A + B));
    float t  = q * fmaf(0.5f, u0, -C);
    g[0] = 2.0f * (w + t);
    g[1] = 2.0f * (w - t);
    g[2] = b * fmaf(-2.0f, C, u0);
}

__global__ __launch_bounds__(256) void kan_grad(
        const float* __restrict__ strain, float* __restrict__ out, int n,
        const float* __restrict__ c0, const float* __restrict__ sb0,
        const float* __restrict__ sp0, const float* __restrict__ b0,
        const float* __restrict__ c1, const float* __restrict__ sb1,
        const float* __restrict__ sp1, const float* __restrict__ ki0,
        const float* __restrict__ ki1) {
    __shared__ float4 tab4[96];   // 4 tables x 12 cells x {value, deriv}

    const int t = threadIdx.x;

    Params P;
    P.sb0_0 = sb0[0]; P.sb0_1 = sb0[1]; P.sb0_2 = sb0[2];
    P.b0 = b0[0]; P.sb1 = sb1[0];
    float k = ki0[0], l = ki1[0];
    P.k3 = k * (1.0f / 3.0f);
    P.k6 = k * (1.0f / 6.0f);
    P.kh = k * 0.5f;
    P.cL = l * 0.34657359f;
    P.ch = l * 0.5f;

    if (t < 48) {
        int tbl = t / 12, cell = t % 12;
        float scale = (tbl < 3) ? sp0[tbl] : sp1[0];
        const float* cp = (tbl < 3) ? (c0 + tbl * NB) : c1;
        int  c    = cell - 1;                  // real cell index 0..8
        bool real = (cell >= 1 && cell <= 9);
        float cv[4];
#pragma unroll
        for (int kk = 0; kk < 4; ++kk) {
            int j = c + kk - 3;
            cv[kk] = (real && j >= 0 && j < NB) ? cp[j] : 0.0f;
        }
        const float c16 = 1.0f / 6.0f;
        float a0 = (cv[0] + 4.0f * cv[1] + cv[2]) * c16 * scale;
        float a1 = (cv[2] - cv[0]) * 0.5f * scale;
        float a2 = (cv[0] - 2.0f * cv[1] + cv[2]) * 0.5f * scale;
        float a3 = (cv[3] - cv[0] + 3.0f * (cv[1] - cv[2])) * c16 * scale;
        tab4[2 * t]     = make_float4(a0, a1, a2, a3);
        tab4[2 * t + 1] = make_float4(1.5f * a1, 3.0f * a2, 4.5f * a3, 0.0f);
    }
    __syncthreads();

    // ---- per-thread analytic g0 at s=0 (x0=x1=1 -> cell 7 f=0; x2=0 -> cell 5
    // f=0.5; irr=0 -> t-term and g2 vanish; silu(1),silu'(1),silu'(0) constant).
    const float SI1 = 0.73105858f, DSI1 = 0.92767051f;
    float S0g = tab4[2 * 7].x,        D0g = tab4[2 * 7 + 1].x;
    float S1g = tab4[2 * 19].x,       D1g = tab4[2 * 19 + 1].x;
    float4 A2 = tab4[2 * 29],         B2  = tab4[2 * 29 + 1];
    const float fh = 0.5f;
    float S2g = fmaf(fmaf(fmaf(A2.w, fh, A2.z), fh, A2.y), fh, A2.x);
    float D2g = fmaf(fmaf(B2.z, fh, B2.y), fh, B2.x);
    float hacc0 = P.b0 + fmaf(P.sb0_0, SI1, S0g) + fmaf(P.sb0_1, SI1, S1g) + S2g;
    float gx0g = fmaf(P.sb0_0, DSI1, D0g);
    float gx1g = fmaf(P.sb0_1, DSI1, D1g);
    float gx2g = fmaf(P.sb0_2, 0.5f, D2g);
    float dW0 = fmaf(P.sb1, silu_d(hacc0), spline_d(hacc0, tab4 + 72));
    float P0g = dW0 * gx0g, P1g = dW0 * gx1g, w2g = dW0 * gx2g;
    float Ag = P.kh * P0g, Bg = P.kh * P1g;
    float Cg = fmaf(-P.k6, P0g + P1g, P.ch * w2g);
    const float G = (Ag + Bg) + 2.0f * Cg;     // g0 = (G, G, 0)

    const int ngroups = (n + 3) >> 2;  // 4 samples (= 3 float4) per thread-task
    for (int gi = blockIdx.x * blockDim.x + t; gi < ngroups;
         gi += gridDim.x * blockDim.x) {
        int i0 = gi * 4;
        if (i0 + 4 <= n) {
            const float4* sp4 = reinterpret_cast<const float4*>(strain + (size_t)i0 * 3);
            float4 v0 = sp4[0], v1 = sp4[1], v2 = sp4[2];
            float in[12] = { v0.x, v0.y, v0.z, v0.w,
                             v1.x, v1.y, v1.z, v1.w,
                             v2.x, v2.y, v2.z, v2.w };
            float o[12];
#pragma unroll
            for (int kk = 0; kk < 4; ++kk) {
                float g[3];
                grad_sample(in[3 * kk], in[3 * kk + 1], in[3 * kk + 2], P, tab4, g);
                o[3 * kk]     = g[0] - G;
                o[3 * kk + 1] = g[1] - G;
                o[3 * kk + 2] = g[2];
            }
            float4* op4 = reinterpret_cast<float4*>(out + (size_t)i0 * 3);
            op4[0] = make_float4(o[0], o[1], o[2],  o[3]);
            op4[1] = make_float4(o[4], o[5], o[6],  o[7]);
            op4[2] = make_float4(o[8], o[9], o[10], o[11]);
        } else {
            for (int i = i0; i < n; ++i) {
                float g[3];
                grad_sample(strain[3 * i], strain[3 * i + 1], strain[3 * i + 2], P,
                            tab4, g);
                out[3 * i]     = g[0] - G;
                out[3 * i + 1] = g[1] - G;
                out[3 * i + 2] = g[2];
            }
        }
    }
}

extern "C" void kernel_launch(void* const* d_in, const int* in_sizes, int n_in,
                              void* d_out, int out_size, void* d_ws, size_t ws_size,
                              hipStream_t stream) {
    const float* strain = (const float*)d_in[0];
    const float* c0  = (const float*)d_in[1];
    const float* sb0 = (const float*)d_in[2];
    const float* sp0 = (const float*)d_in[3];
    const float* b0  = (const float*)d_in[4];
    const float* c1  = (const float*)d_in[5];
    const float* sb1 = (const float*)d_in[6];
    const float* sp1 = (const float*)d_in[7];
    // d_in[8] = b1: no effect on gradient
    const float* ki0 = (const float*)d_in[9];
    const float* ki1 = (const float*)d_in[10];

    int n = in_sizes[0] / 3;                 // number of samples
    int ngroups = (n + 3) / 4;
    int block = 256;
    int grid = (ngroups + block - 1) / block;
    if (grid > 8192) grid = 8192;

    kan_grad<<<grid, block, 0, stream>>>(strain, (float*)d_out, n,
                                         c0, sb0, sp0, b0, c1, sb1, sp1, ki0, ki1);
}